// Round 5
// baseline (53.156 us; speedup 1.0000x reference)
//
#include <hip/hip_runtime.h>
#include <math.h>

#define B_N 65536
#define C_N 100
constexpr float ALPHA = 0.01f;
constexpr float TAU   = 2.0f;
constexpr float TEMP  = 2.0f;
constexpr float EPSF  = 1e-9f;
constexpr float NEG_SENT = -1.0e30f;   // sentinel: exp(x*k)=0, finite (no NaN in a-x)

// ---------------- DPP reduction helpers (VALU-only) ----------------
// After rowsum32, ALL lanes with (lane&31)>=16 hold the 32-group total.
template<int CTRL>
__device__ __forceinline__ float fadd_dpp(float x) {
    return x + __int_as_float(__builtin_amdgcn_update_dpp(
        0, __float_as_int(x), CTRL, 0xF, 0xF, true));
}
__device__ __forceinline__ float rowsum32(float x) {
    x = fadd_dpp<0xB1>(x);    // quad_perm xor1
    x = fadd_dpp<0x4E>(x);    // quad_perm xor2
    x = fadd_dpp<0x124>(x);   // row_ror:4
    x = fadd_dpp<0x128>(x);   // row_ror:8
    x = fadd_dpp<0x142>(x);   // row_bcast15
    return x;
}
template<int CTRL>
__device__ __forceinline__ void amax_dpp(unsigned &hi, unsigned &lo) {
    const unsigned yh = (unsigned)__builtin_amdgcn_update_dpp(0, (int)hi, CTRL, 0xF, 0xF, true);
    const unsigned yl = (unsigned)__builtin_amdgcn_update_dpp(0, (int)lo, CTRL, 0xF, 0xF, true);
    const bool take = (yh > hi) || (yh == hi && yl > lo);
    hi = take ? yh : hi;
    lo = take ? yl : lo;
}
__device__ __forceinline__ void rowamax32(unsigned &hi, unsigned &lo) {
    amax_dpp<0xB1>(hi, lo);
    amax_dpp<0x4E>(hi, lo);
    amax_dpp<0x124>(hi, lo);
    amax_dpp<0x128>(hi, lo);
    amax_dpp<0x142>(hi, lo);
}

__device__ __forceinline__ float wsum(float v) {
    #pragma unroll
    for (int o = 32; o; o >>= 1) v += __shfl_xor(v, o);
    return v;
}

// ---------- prep: bincount (0-255) + prior (256) + cos softmax (257-260) ----------
__global__ void prep_k(const float* __restrict__ cosf, const float* __restrict__ prior,
                       const int* __restrict__ target,
                       float* __restrict__ sm, float* __restrict__ lp, float* __restrict__ c3,
                       int* __restrict__ counts) {
    const int b = blockIdx.x;
    if (b < 256) {
        __shared__ int h[C_N];
        for (int i = threadIdx.x; i < C_N; i += blockDim.x) h[i] = 0;
        __syncthreads();
        const int gid = b * blockDim.x + threadIdx.x;
        const int stride = 256 * blockDim.x;
        for (int i = gid; i < B_N; i += stride) atomicAdd(&h[target[i]], 1);
        __syncthreads();
        for (int i = threadIdx.x; i < C_N; i += blockDim.x)
            if (h[i]) atomicAdd(&counts[i], h[i]);
    } else if (b == 256) {
        __shared__ float sp[C_N];
        __shared__ float val[C_N];
        const int t = threadIdx.x;
        if (t < C_N) sp[t] = prior[t];
        __syncthreads();
        int rank = 0;
        float lpi = 0.f;
        if (t < C_N) {
            const float pi = sp[t];
            for (int j = 0; j < C_N; ++j) {
                const float pj = sp[j];
                rank += (pj < pi) || (pj == pi && j < t);   // stable argsort rank
            }
            val[rank] = pi;
            lpi = __logf(pi + EPSF);
            lp[t] = lpi;
        }
        __syncthreads();
        if (t < C_N) {
            const float inv = val[C_N - 1 - rank];
            c3[t] = lpi - TAU * __logf(inv + EPSF);
        }
    } else {
        const int gw = (b - 257) * 4 + (threadIdx.x >> 6);   // 0..15
        const int lane = threadIdx.x & 63;
        for (int row = gw; row < C_N; row += 16) {
            const float* rp = cosf + row * C_N;
            const float v0 = rp[lane];
            const bool has1 = (lane + 64) < C_N;
            const float v1 = has1 ? rp[lane + 64] : -INFINITY;
            float m = fmaxf(v0, v1);
            #pragma unroll
            for (int o = 32; o; o >>= 1) m = fmaxf(m, __shfl_xor(m, o));
            const float e0 = __expf(v0 - m);
            const float e1 = has1 ? __expf(v1 - m) : 0.f;
            const float s = wsum(e0 + e1);
            const float is = 1.0f / s;
            sm[row * C_N + lane] = e0 * is;
            if (has1) sm[row * C_N + lane + 64] = e1 * is;
        }
    }
}

// ---------- main: ONE row-pair per wave, max TLP ----------
#define NBLK 8192                       // 4 waves/block * 2 rows/wave = 8 rows/block

__launch_bounds__(256)
__global__ void main_k(const int* __restrict__ target,
                       const float* __restrict__ e1p, const float* __restrict__ e2p,
                       const float* __restrict__ e3p, const float* __restrict__ opp,
                       const float* __restrict__ outp,
                       const float* __restrict__ sm, const float* __restrict__ lp,
                       const float* __restrict__ c3, const int* __restrict__ counts,
                       float* __restrict__ dout,
                       float* __restrict__ ploss, float* __restrict__ pkl, float* __restrict__ pn) {
    const int lane = threadIdx.x & 63;
    const int gl   = lane & 31;
    const int half = lane >> 5;
    const int wslot = threadIdx.x >> 6;
    const int gw   = blockIdx.x * 4 + wslot;
    const bool act = gl < 25;
    const int c0 = 4 * gl;

    const int row = 2 * gw + half;
    const int tgt = target[row];
    const float rc = 1.0f / (float)counts[tgt];
    const int base = row * C_N;

    float4 LP = make_float4(0,0,0,0), CO = make_float4(0,0,0,0);
    float4 E1, E2, E3, OP, OU, SM;
    E1 = E2 = E3 = OP = OU = make_float4(NEG_SENT, NEG_SENT, NEG_SENT, NEG_SENT);
    SM = make_float4(0,0,0,0);
    if (act) {
        LP = *(const float4*)(lp + c0);
        CO = *(const float4*)(c3 + c0);
        E1 = *(const float4*)(e1p + base + c0);
        E2 = *(const float4*)(e2p + base + c0);
        E3 = *(const float4*)(e3p + base + c0);
        OP = *(const float4*)(opp + base + c0);
        OU = *(const float4*)(outp + base + c0);
        SM = *(const float4*)(sm + tgt * C_N + c0);
    }

    // soft labels (inactive: SM=0, c0>=100 != tgt -> 0)
    const float la0 = (1.0f - ALPHA) * (c0     == tgt) + ALPHA * SM.x;
    const float la1 = (1.0f - ALPHA) * (c0 + 1 == tgt) + ALPHA * SM.y;
    const float la2 = (1.0f - ALPHA) * (c0 + 2 == tgt) + ALPHA * SM.z;
    const float la3 = (1.0f - ALPHA) * (c0 + 3 == tgt) + ALPHA * SM.w;

    const float l20 = E2.x + LP.x, l21 = E2.y + LP.y, l22 = E2.z + LP.z, l23 = E2.w + LP.w;
    const float l30 = E3.x + CO.x, l31 = E3.y + CO.y, l32 = E3.z + CO.z, l33 = E3.w + CO.w;

    // partition functions, no max shift (|real logits| <= ~19; sentinel -> exp = 0)
    float s1 = __expf(E1.x) + __expf(E1.y) + __expf(E1.z) + __expf(E1.w);
    float s2 = __expf(l20) + __expf(l21) + __expf(l22) + __expf(l23);
    float s3 = __expf(l30) + __expf(l31) + __expf(l32) + __expf(l33);
    float dt = la0 * (E1.x + l20 + l30) + la1 * (E1.y + l21 + l31)
             + la2 * (E1.z + l22 + l32) + la3 * (E1.w + l23 + l33);

    // teacher probs at m=0
    const float a0 = OP.x * 0.5f, a1 = OP.y * 0.5f, a2 = OP.z * 0.5f, a3 = OP.w * 0.5f;
    const float p0 = __expf(a0), p1 = __expf(a1), p2 = __expf(a2), p3 = __expf(a3);
    float zt = p0 + p1 + p2 + p3;

    // local argmax candidate (first-index tiebreak); sentinel never wins
    float bv = OP.x; int bi = c0;
    if (OP.y > bv) { bv = OP.y; bi = c0 + 1; }
    if (OP.z > bv) { bv = OP.z; bi = c0 + 2; }
    if (OP.w > bv) { bv = OP.w; bi = c0 + 3; }
    unsigned bb = __float_as_uint(bv);
    bb = ((int)bb < 0) ? ~bb : (bb | 0x80000000u);
    unsigned khi = bb, klo = (unsigned)~bi;

    // student
    const float es0 = OU.x * rc, es1 = OU.y * rc, es2 = OU.z * rc, es3 = OU.w * rc;
    const float x0 = es0 * 0.5f, x1 = es1 * 0.5f, x2 = es2 * 0.5f, x3 = es3 * 0.5f;
    float zs = __expf(x0) + __expf(x1) + __expf(x2) + __expf(x3);
    float D  = p0 * (a0 - x0) + p1 * (a1 - x1) + p2 * (a2 - x2) + p3 * (a3 - x3);

    // DPP reductions; results valid on lanes with (lane&31)>=16
    s1 = rowsum32(s1);
    s2 = rowsum32(s2);
    s3 = rowsum32(s3);
    dt = rowsum32(dt);
    zt = rowsum32(zt);
    zs = rowsum32(zs);
    D  = rowsum32(D);
    rowamax32(khi, klo);

    const float ce  = __logf(s1 * s2 * s3) - dt;
    const int   mi  = (int)~klo;
    const float rzt = 1.0f / zt;
    const float kl  = D * rzt + __logf(zs * rzt);
    const bool  sel = (mi == tgt);

    if (act) {
        *(float2*)(dout + 2 + base + c0)     = make_float2(es0, es1);
        *(float2*)(dout + 2 + base + c0 + 2) = make_float2(es2, es3);
    }

    // wave combine: pick owner lanes 16 (row half=0) and 48 (half=1)
    const float klm = sel ? kl : 0.f;
    const float nm  = sel ? 1.f : 0.f;
    const float lossW = __shfl(ce, 16) + __shfl(ce, 48);
    const float klW   = __shfl(klm, 16) + __shfl(klm, 48);
    const float nW    = __shfl(nm, 16) + __shfl(nm, 48);

    __shared__ float bl[4], bk[4], bn[4];
    if (lane == 0) { bl[wslot] = lossW; bk[wslot] = klW; bn[wslot] = nW; }
    __syncthreads();
    if (threadIdx.x == 0) {
        ploss[blockIdx.x] = bl[0] + bl[1] + bl[2] + bl[3];
        pkl[blockIdx.x]   = bk[0] + bk[1] + bk[2] + bk[3];
        pn[blockIdx.x]    = bn[0] + bn[1] + bn[2] + bn[3];
    }
}

// ---------- final reduction ----------
__global__ void final_k(const float* __restrict__ ploss, const float* __restrict__ pkl,
                        const float* __restrict__ pn, float* __restrict__ dout) {
    __shared__ float sl[256], sk[256], sn[256];
    const int t = threadIdx.x;
    float l = 0.f, k = 0.f, n = 0.f;
    for (int i = t; i < NBLK; i += 256) { l += ploss[i]; k += pkl[i]; n += pn[i]; }
    sl[t] = l; sk[t] = k; sn[t] = n;
    __syncthreads();
    for (int s = 128; s; s >>= 1) {
        if (t < s) { sl[t] += sl[t + s]; sk[t] += sk[t + s]; sn[t] += sn[t + s]; }
        __syncthreads();
    }
    if (t == 0) {
        dout[0] = sl[0] / (float)B_N;
        const float kl = (sn[0] > 0.f) ? (sk[0] / fmaxf(sn[0], 1.f)) : 0.f;
        dout[1] = kl * (TEMP * TEMP) * 3.0f;
    }
}

extern "C" void kernel_launch(void* const* d_in, const int* in_sizes, int n_in,
                              void* d_out, int out_size, void* d_ws, size_t ws_size,
                              hipStream_t stream) {
    const int*   target = (const int*)  d_in[1];
    const float* cosf   = (const float*)d_in[2];
    const float* oldp   = (const float*)d_in[3];
    const float* e1     = (const float*)d_in[4];
    const float* e2     = (const float*)d_in[5];
    const float* e3     = (const float*)d_in[6];
    const float* outp   = (const float*)d_in[7];
    const float* prior  = (const float*)d_in[8];

    float* ws    = (float*)d_ws;
    float* sm    = ws;                 // [10000]
    float* lp    = ws + 10000;         // [100]
    float* c3    = ws + 10100;         // [100]
    int*   cnts  = (int*)(ws + 10200); // [100]
    float* ploss = ws + 10304;         // [NBLK]
    float* pkl   = ploss + NBLK;       // [NBLK]
    float* pn    = pkl + NBLK;         // [NBLK]

    hipMemsetAsync(cnts, 0, C_N * sizeof(int), stream);
    prep_k<<<261, 256, 0, stream>>>(cosf, prior, target, sm, lp, c3, cnts);
    main_k<<<NBLK, 256, 0, stream>>>(target, e1, e2, e3, oldp, outp,
                                     sm, lp, c3, cnts, (float*)d_out, ploss, pkl, pn);
    final_k<<<1, 256, 0, stream>>>(ploss, pkl, pn, (float*)d_out);
}